// Round 8
// baseline (74.932 us; speedup 1.0000x reference)
//
#include <hip/hip_runtime.h>
#include <stdint.h>

// SmoothLoss: total = (1/24) * sum over 24 offsets of mean( exp(-||dx||^2/200) * ||dy||_1 )
// x = rgb2ycbcr(input) (bias cancels in diffs), y = output. 12 offsets, weight 2x.
// R7: half-width tiles (COLS=264 incl 4+4 halo), TH=4 own rows + 2 bottom halo.
// LDS 38KB -> 4 blocks/CU (16 waves/CU). ONE barrier per block:
//   waves 0-2: reg-stage input rgb (2 rows each), convert to K2-scaled ycbcr in
//              registers (no Phase B), POISON select folded in, ds_write_b128.
//   wave 3:    global_load_lds the 3 output planes for all 6 rows (async).
// Poison: only X-plane-0 halo needs 1e19 (w = exp2(-1e38) = 0 kills the term;
// garbage finite Y/x1/x2 values are multiplied by w=0). No bounds checks in
// the hot loop. wgt = exp2f(-q) with K2 = sqrt(0.005/ln2) baked into coeffs.

#define B_ 16
#define H_ 512
#define W_ 512
#define HW_ (H_ * W_)
#define CHW_ (3 * HW_)

#define TH 4          // own rows per block
#define ROWS 6        // TH + 2 bottom halo
#define COLS 264      // 4 halo | 256 own | 4 halo ; img col jbase+c-4 <-> lds col c
#define NTHREADS 256
#define POISON 1e19f
#define K2 0.08493218049364766f  // sqrt(0.005 / ln(2))

__global__ void zero_out_kernel(float* p) { p[0] = 0.0f; }

__device__ __forceinline__ void gload16(const float* gsrc, float* ldst) {
  __builtin_amdgcn_global_load_lds(
      (const __attribute__((address_space(1))) void*)gsrc,
      (__attribute__((address_space(3))) void*)ldst, 16, 0, 0);
}

// O[plane][q]: q <-> own img col +q (8 floats)
template <int DW>
__device__ __forceinline__ float contrib0(const float (&O)[6][8]) {
  const float scale = 2.0f / (24.0f * (float)B_ * (float)H_ * (float)(W_ - DW));
  float s = 0.0f;
#pragma unroll
  for (int p = 0; p < 4; ++p) {
    float d0 = O[0][p] - O[0][p + DW];
    float d1 = O[1][p] - O[1][p + DW];
    float d2 = O[2][p] - O[2][p + DW];
    float nq = -(d0 * d0 + d1 * d1 + d2 * d2);
    float wgt = exp2f(nq);
    float l1 = fabsf(O[3][p] - O[3][p + DW]) + fabsf(O[4][p] - O[4][p + DW]) +
               fabsf(O[5][p] - O[5][p + DW]);
    s += wgt * l1;
  }
  return scale * s;
}

// N[plane][q]: q <-> own img col -4+q (12 floats)
template <int DH, int DW>
__device__ __forceinline__ float contribN(const float (&O)[6][8],
                                          const float (&N)[6][12]) {
  constexpr int AW = DW < 0 ? -DW : DW;
  const float scale =
      2.0f / (24.0f * (float)B_ * (float)(H_ - DH) * (float)(W_ - AW));
  float s = 0.0f;
#pragma unroll
  for (int p = 0; p < 4; ++p) {
    const int ni = p + 4 + DW;
    float d0 = O[0][p] - N[0][ni];
    float d1 = O[1][p] - N[1][ni];
    float d2 = O[2][p] - N[2][ni];
    float nq = -(d0 * d0 + d1 * d1 + d2 * d2);
    float wgt = exp2f(nq);
    float l1 = fabsf(O[3][p] - N[3][ni]) + fabsf(O[4][p] - N[4][ni]) +
               fabsf(O[5][p] - N[5][ni]);
    s += wgt * l1;
  }
  return scale * s;
}

__device__ __forceinline__ void stage_x_row(const float* __restrict__ inb,
                                            int graw, int jbase, int lane,
                                            float (*ldsp)[ROWS][COLS], int rr) {
  const bool rowOOB = (graw >= H_);
  const int gr = rowOOB ? (H_ - 1) : graw;
  const float* rowp = inb + (size_t)gr * W_;

  // main: lds cols 4*lane .. 4*lane+3  <-> img cols jbase-4+4*lane ..
  const int cimg = jbase - 4 + 4 * lane;
  const int c = cimg < 0 ? 0 : cimg;
  const bool po = rowOOB || (cimg < 0);
  float4 rv = *(const float4*)(rowp + c);
  float4 gv = *(const float4*)(rowp + HW_ + c);
  float4 bv = *(const float4*)(rowp + 2 * HW_ + c);

  // extra (lanes 0,1): lds cols 256+4*lane <-> img cols jbase+252+4*lane
  const int c2img = jbase + 252 + 4 * lane;
  const int c2 = c2img > W_ - 4 ? W_ - 4 : c2img;
  const bool po2 = rowOOB || (c2img >= W_);
  float4 rv2, gv2, bv2;
  if (lane < 2) {
    rv2 = *(const float4*)(rowp + c2);
    gv2 = *(const float4*)(rowp + HW_ + c2);
    bv2 = *(const float4*)(rowp + 2 * HW_ + c2);
  }

  {
    float rA[4] = {rv.x, rv.y, rv.z, rv.w};
    float gA[4] = {gv.x, gv.y, gv.z, gv.w};
    float bA[4] = {bv.x, bv.y, bv.z, bv.w};
    float x0[4], x1[4], x2[4];
#pragma unroll
    for (int m = 0; m < 4; ++m) {
      x0[m] = po ? POISON
                 : (0.257f * K2) * rA[m] + (0.564f * K2) * gA[m] +
                       (0.098f * K2) * bA[m];
      x1[m] = (-0.148f * K2) * rA[m] + (-0.291f * K2) * gA[m] +
              (0.439f * K2) * bA[m];
      x2[m] = (0.439f * K2) * rA[m] + (-0.368f * K2) * gA[m] +
              (-0.071f * K2) * bA[m];
    }
    *(float4*)&ldsp[0][rr][4 * lane] = make_float4(x0[0], x0[1], x0[2], x0[3]);
    *(float4*)&ldsp[1][rr][4 * lane] = make_float4(x1[0], x1[1], x1[2], x1[3]);
    *(float4*)&ldsp[2][rr][4 * lane] = make_float4(x2[0], x2[1], x2[2], x2[3]);
  }
  if (lane < 2) {
    float rA[4] = {rv2.x, rv2.y, rv2.z, rv2.w};
    float gA[4] = {gv2.x, gv2.y, gv2.z, gv2.w};
    float bA[4] = {bv2.x, bv2.y, bv2.z, bv2.w};
    float x0[4], x1[4], x2[4];
#pragma unroll
    for (int m = 0; m < 4; ++m) {
      x0[m] = po2 ? POISON
                  : (0.257f * K2) * rA[m] + (0.564f * K2) * gA[m] +
                        (0.098f * K2) * bA[m];
      x1[m] = (-0.148f * K2) * rA[m] + (-0.291f * K2) * gA[m] +
              (0.439f * K2) * bA[m];
      x2[m] = (0.439f * K2) * rA[m] + (-0.368f * K2) * gA[m] +
              (-0.071f * K2) * bA[m];
    }
    *(float4*)&ldsp[0][rr][256 + 4 * lane] =
        make_float4(x0[0], x0[1], x0[2], x0[3]);
    *(float4*)&ldsp[1][rr][256 + 4 * lane] =
        make_float4(x1[0], x1[1], x1[2], x1[3]);
    *(float4*)&ldsp[2][rr][256 + 4 * lane] =
        make_float4(x2[0], x2[1], x2[2], x2[3]);
  }
}

__global__ __launch_bounds__(NTHREADS, 4) void smooth_loss_kernel(
    const float* __restrict__ in, const float* __restrict__ outp,
    float* __restrict__ result) {
  __shared__ alignas(16) float lds[6][ROWS][COLS];  // 38,016 B
  __shared__ float wsum[4];

  const int tid = threadIdx.x;
  const int wv = tid >> 6;
  const int lane = tid & 63;
  const int by = blockIdx.x;       // 0..127 row tile
  const int half = blockIdx.y;     // 0..1
  const int b = blockIdx.z;        // 0..15
  const int ibase = by * TH;
  const int jbase = half * 256;

  const float* inb = in + (size_t)b * CHW_;
  const float* outb = outp + (size_t)b * CHW_;

  if (wv == 3) {
    // ---- Y staging: all 6 rows x 3 planes via global_load_lds ----
#pragma unroll
    for (int r = 0; r < ROWS; ++r) {
      int graw = ibase + r;
      int gr = graw < H_ - 1 ? graw : H_ - 1;  // clamp (garbage benign, w=0)
      const float* rowp = outb + (size_t)gr * W_;
      int c = jbase - 4 + 4 * lane;
      c = c < 0 ? 0 : c;
#pragma unroll
      for (int p = 0; p < 3; ++p) gload16(rowp + (size_t)p * HW_ + c, &lds[3 + p][r][0]);
      if (lane < 2) {
        int c2 = jbase + 252 + 4 * lane;
        c2 = c2 > W_ - 4 ? W_ - 4 : c2;
#pragma unroll
        for (int p = 0; p < 3; ++p)
          gload16(rowp + (size_t)p * HW_ + c2, &lds[3 + p][r][256]);
      }
    }
  } else {
    // ---- X staging: wave wv handles rows 2wv, 2wv+1 (reg-staged + convert) ----
    stage_x_row(inb, ibase + 2 * wv, jbase, lane, lds, 2 * wv);
    stage_x_row(inb, ibase + 2 * wv + 1, jbase, lane, lds, 2 * wv + 1);
  }

  __syncthreads();  // single barrier: drains gloads (vmcnt) + ds_writes (lgkm)

  // ---- compute: wave wv owns row wv; lane -> own img cols jbase+4*lane.. ----
  const int jl = 4 * lane;

  float acc = 0.0f;
  float O[6][8];
#pragma unroll
  for (int p6 = 0; p6 < 6; ++p6) {
    *(float4*)&O[p6][0] = *(const float4*)&lds[p6][wv][jl + 4];
    *(float4*)&O[p6][4] = *(const float4*)&lds[p6][wv][jl + 8];
  }

  acc += contrib0<1>(O);
  acc += contrib0<2>(O);

  {
    float N[6][12];
#pragma unroll
    for (int p6 = 0; p6 < 6; ++p6) {
      *(float4*)&N[p6][0] = *(const float4*)&lds[p6][wv + 1][jl];
      *(float4*)&N[p6][4] = *(const float4*)&lds[p6][wv + 1][jl + 4];
      *(float4*)&N[p6][8] = *(const float4*)&lds[p6][wv + 1][jl + 8];
    }
    acc += contribN<1, -2>(O, N);
    acc += contribN<1, -1>(O, N);
    acc += contribN<1, 0>(O, N);
    acc += contribN<1, 1>(O, N);
    acc += contribN<1, 2>(O, N);
  }
  {
    float N[6][12];
#pragma unroll
    for (int p6 = 0; p6 < 6; ++p6) {
      *(float4*)&N[p6][0] = *(const float4*)&lds[p6][wv + 2][jl];
      *(float4*)&N[p6][4] = *(const float4*)&lds[p6][wv + 2][jl + 4];
      *(float4*)&N[p6][8] = *(const float4*)&lds[p6][wv + 2][jl + 8];
    }
    acc += contribN<2, -2>(O, N);
    acc += contribN<2, -1>(O, N);
    acc += contribN<2, 0>(O, N);
    acc += contribN<2, 1>(O, N);
    acc += contribN<2, 2>(O, N);
  }

  // ---- reduction ----
#pragma unroll
  for (int o = 32; o > 0; o >>= 1) acc += __shfl_down(acc, o, 64);
  if (lane == 0) wsum[wv] = acc;
  __syncthreads();
  if (tid == 0) {
    atomicAdd(result, wsum[0] + wsum[1] + wsum[2] + wsum[3]);
  }
}

extern "C" void kernel_launch(void* const* d_in, const int* in_sizes, int n_in,
                              void* d_out, int out_size, void* d_ws, size_t ws_size,
                              hipStream_t stream) {
  const float* in = (const float*)d_in[0];
  const float* outp = (const float*)d_in[1];
  float* res = (float*)d_out;

  zero_out_kernel<<<1, 1, 0, stream>>>(res);

  dim3 grid(H_ / TH, 2, B_);  // (128, 2, 16) = 4096 blocks
  smooth_loss_kernel<<<grid, NTHREADS, 0, stream>>>(in, outp, res);
}